// Round 8
// baseline (650.699 us; speedup 1.0000x reference)
//
#include <hip/hip_runtime.h>

// x [32,64,64,64] f32, emb [64,1024] f32
// N = 131072 pixels, D = 64, K = 1024
// out = [ result: 8388608 f32 ][ argmin-as-f32: 131072 ]
//
// Round 12: back to the PROVEN R9 structure (90us, absmax 0.0, VGPR 64,
// zero scratch; R10/R11's hand-waitcnt pipelines both spilled and are
// abandoned). One change: K-SPLIT ACROSS BLOCKS to lift the grid-capped
// occupancy (R9: 1024 blocks = exactly 4 blocks/CU = 50% ceiling; VGPR
// and LDS both allowed 8+).
//  - vq: 2048 blocks; block g does k-half (g>>10), pixels (g&1023)*128.
//    16 t-iters of the identical R9 loop. Writes per-pixel (bestv,bestk)
//    for its half to workspace (2MB). __launch_bounds__(256,8): 8
//    blocks/CU co-resident.
//  - merge kernel: picks half1 iff v1 < v0 (ties -> half0 = smaller k,
//    same as the sequential scan), writes outidx + gathers fp32 rows.
//    This is R9's tail phase relocated, 512x256.
//  - prep: R10/R11's 36x256 parallel version (correctness-proven twice).

using half8  = __attribute__((ext_vector_type(8))) _Float16;
using f32x16 = __attribute__((ext_vector_type(16))) float;

__global__ void prep_kernel(const float* __restrict__ emb,
                            float* __restrict__ e2,
                            _Float16* __restrict__ eTh,
                            _Float16* __restrict__ eTl) {
    const int b = blockIdx.x;
    const int t = threadIdx.x;
    if (b < 32) {
        // h/l split: c from block (uniform), k lane-contiguous -> coalesced.
        const int c = b >> 2;                 // 0..7
        const int k = (b & 3) * 256 + t;      // 0..1023
        half8 hv, lv;
#pragma unroll
        for (int j = 0; j < 8; ++j) {
            float v = emb[(c * 8 + j) * 1024 + k];
            _Float16 h = (_Float16)v;          // same split as round 1
            hv[j] = h;
            lv[j] = (_Float16)(v - (float)h);  // exact residual
        }
        *(half8*)(eTh + k * 64 + c * 8) = hv;
        *(half8*)(eTl + k * 64 + c * 8) = lv;
    } else {
        // e2: one thread per k, ascending-d fmaf chain - bit-identical
        // op sequence to the original prep.
        const int k = (b - 32) * 256 + t;
        float s = 0.f;
#pragma unroll
        for (int d = 0; d < 64; ++d) {
            float v = emb[(d << 10) + k];
            s = fmaf(v, v, s);
        }
        e2[k] = s;
    }
}

__launch_bounds__(256, 8)
__global__ void vq_kernel(const float* __restrict__ x,
                          const _Float16* __restrict__ eTh,
                          const _Float16* __restrict__ eTl,
                          const float* __restrict__ e2,
                          float* __restrict__ wbest,
                          int* __restrict__ wkid) {
    __shared__ __align__(16) _Float16 sB[2][4096];  // [buf][h:2048 | l:2048]

    const int tx   = threadIdx.x;
    const int gid  = blockIdx.x;
    const int half = gid >> 10;              // 0: k<512, 1: k>=512
    const int n0   = (gid & 1023) * 128;
    const int bb   = n0 >> 12;
    const int hw   = n0 & 4095;
    const float* xbase = x + bb * 262144 + hw;
    const int tbase = half << 4;             // first t of this half

    const int lane = tx & 63;
    const int w    = tx >> 6;
    const int c    = lane & 31;    // 32x32 col / A-row
    const int hi   = lane >> 5;    // k-half selector
    const int pxb  = w << 5;       // wave's 32-pixel base

    // ---- A-fragments straight from global (identical values to staged) ----
    half8 ah[4], al[4];
#pragma unroll
    for (int ch = 0; ch < 4; ++ch) {
#pragma unroll
        for (int j = 0; j < 8; ++j) {
            float v = xbase[(ch * 16 + hi * 8 + j) * 4096 + pxb + c];
            _Float16 h = (_Float16)v;
            ah[ch][j] = h;
            al[ch][j] = (_Float16)(v - (float)h);
        }
    }
    asm volatile("" ::: "memory");   // keep fragments register-resident

    // ---- swizzled LDS read offsets for B (invariant over t) ----------------
    int Dofs[4];
#pragma unroll
    for (int ch = 0; ch < 4; ++ch) {
        const int y = c * 128 + ch * 32 + hi * 16;
        Dofs[ch] = y ^ ((c & 7) << 4);
    }

    // ---- staging source: pre-swizzled per-thread global byte offset --------
    const int Lb = tx * 16;                        // linear byte in 4KB tile
    const int Sb = Lb ^ (((Lb >> 7) & 7) << 4);    // sigma (self-inverse)
    const char* gH = (const char*)eTh + Sb + (tbase << 12);
    const char* gL = (const char*)eTl + Sb + (tbase << 12);

#define STAGE(BUF, IT)                                                        \
    {                                                                         \
        __builtin_amdgcn_global_load_lds(                                     \
            (const __attribute__((address_space(1))) unsigned int*)(gH + ((IT) << 12)), \
            (__attribute__((address_space(3))) unsigned int*)(sB[BUF] + (w << 9)),       \
            16, 0, 0);                                                        \
        __builtin_amdgcn_global_load_lds(                                     \
            (const __attribute__((address_space(1))) unsigned int*)(gL + ((IT) << 12)), \
            (__attribute__((address_space(3))) unsigned int*)(sB[BUF] + 2048 + (w << 9)),\
            16, 0, 0);                                                        \
    }

    float best[16];
    int   bestt[16];
#pragma unroll
    for (int i = 0; i < 16; ++i) { best[i] = 3.4e38f; bestt[i] = tbase; }

    STAGE(0, 0);
    __syncthreads();   // drains vmcnt(0): buf0 ready

#pragma unroll 1
    for (int it = 0; it < 16; ++it) {
        const int cur = it & 1;
        if (it < 15) STAGE(cur ^ 1, it + 1);      // prefetch next tile
        const int t = tbase + it;

        const float e2v = e2[(t << 5) + c];
        const char* bbase = (const char*)sB[cur];
        half8 bh_[4], bl_[4];
#pragma unroll
        for (int ch = 0; ch < 4; ++ch) {
            bh_[ch] = *(const half8*)(bbase + Dofs[ch]);
            bl_[ch] = *(const half8*)(bbase + 4096 + Dofs[ch]);
        }

        f32x16 a = {};
#pragma unroll
        for (int ch = 0; ch < 4; ++ch)
            a = __builtin_amdgcn_mfma_f32_32x32x16_f16(al[ch], bl_[ch], a, 0, 0, 0);
#pragma unroll
        for (int ch = 0; ch < 4; ++ch)
            a = __builtin_amdgcn_mfma_f32_32x32x16_f16(al[ch], bh_[ch], a, 0, 0, 0);
#pragma unroll
        for (int ch = 0; ch < 4; ++ch)
            a = __builtin_amdgcn_mfma_f32_32x32x16_f16(ah[ch], bl_[ch], a, 0, 0, 0);
#pragma unroll
        for (int ch = 0; ch < 4; ++ch)
            a = __builtin_amdgcn_mfma_f32_32x32x16_f16(ah[ch], bh_[ch], a, 0, 0, 0);

#pragma unroll
        for (int r = 0; r < 16; ++r) {
            float dist = fmaf(-2.f, a[r], e2v);
            if (dist < best[r]) { best[r] = dist; bestt[r] = t; }
        }
        __syncthreads();   // this iter's reads done; prefetch drained
    }

    // ---- per-pixel argmin within this half: butterfly over 32 lanes --------
    // k = t*32 + c; ascending-t strict < kept earliest k per lane; cross-lane
    // merge breaks ties toward smaller k. C layout (verified m74/m101):
    // col = lane&31, row = (r&3) + 8*(r>>2) + 4*hi.
#pragma unroll
    for (int r = 0; r < 16; ++r) {
        float bv = best[r];
        int   bk = (bestt[r] << 5) + c;
#pragma unroll
        for (int m = 1; m < 32; m <<= 1) {
            float ov = __shfl_xor(bv, m, 64);
            int   ok = __shfl_xor(bk, m, 64);
            if (ov < bv || (ov == bv && ok < bk)) { bv = ov; bk = ok; }
        }
        if (c == 0) {
            const int row = (r & 3) + 8 * (r >> 2) + 4 * hi;
            const int pix = n0 + pxb + row;
            wbest[half * 131072 + pix] = bv;
            wkid [half * 131072 + pix] = bk;
        }
    }
}

__global__ void merge_kernel(const float* __restrict__ wbest,
                             const int* __restrict__ wkid,
                             const float* __restrict__ emb,
                             float* __restrict__ outq,
                             float* __restrict__ outidx) {
    const int tx = threadIdx.x;
    const int n0 = blockIdx.x * 256;
    const int p  = n0 + tx;                  // global pixel
    const float v0 = wbest[p];
    const float v1 = wbest[131072 + p];
    const int   k0 = wkid[p];
    const int   k1 = wkid[131072 + p];
    // strict <: half0 wins ties (its k is always smaller) — identical to
    // a single ascending-k scan's first-minimum semantics.
    const int amin = (v1 < v0) ? k1 : k0;
    outidx[p] = (float)amin;

    const int bb = n0 >> 12;
    const int hw = (n0 & 4095) + tx;
    float* obase = outq + bb * 262144 + hw;
#pragma unroll
    for (int d = 0; d < 64; ++d)
        obase[d * 4096] = emb[d * 1024 + amin];
}

extern "C" void kernel_launch(void* const* d_in, const int* in_sizes, int n_in,
                              void* d_out, int out_size, void* d_ws, size_t ws_size,
                              hipStream_t stream) {
    const float* x   = (const float*)d_in[0];
    const float* emb = (const float*)d_in[1];
    float* outq   = (float*)d_out;
    float* outidx = outq + 8388608;            // 32*64*64*64

    float*    e2  = (float*)d_ws;                               // 4 KB
    _Float16* eTh = (_Float16*)((char*)d_ws + 4096);            // 128 KB
    _Float16* eTl = (_Float16*)((char*)d_ws + 4096 + 131072);   // 128 KB
    float*    wbest = (float*)((char*)d_ws + 266240);           // 1 MB
    int*      wkid  = (int*)((char*)d_ws + 266240 + 1048576);   // 1 MB

    prep_kernel<<<36, 256, 0, stream>>>(emb, e2, eTh, eTl);
    vq_kernel<<<2048, 256, 0, stream>>>(x, eTh, eTl, e2, wbest, wkid);
    merge_kernel<<<512, 256, 0, stream>>>(wbest, wkid, emb, outq, outidx);
}

// Round 9
// 181.580 us; speedup vs baseline: 3.5835x; 3.5835x over previous
//
#include <hip/hip_runtime.h>

// x [32,64,64,64] f32, emb [64,1024] f32
// N = 131072 pixels, D = 64, K = 1024
// out = [ result: 8388608 f32 ][ argmin-as-f32: 131072 ]
//
// Round 13: R9 (the proven 90us/absmax-0.0/VGPR-64 kernel) with ONE change:
// BK=64 — stage TWO k-tiles (16KB) per __syncthreads and run two verbatim
// R9 compute halves per barrier-iter (16 barriers instead of 32).
// Rationale: __syncthreads structurally drains vmcnt(0) every iter; R9's
// per-iter compute (~16 MFMA) is too short to cover the L2 broadcast
// latency of its own prefetch, and raw counters show the MFMA pipe only
// ~2% busy. Doubling compute-per-drain and halving drain count amortizes
// the exposed latency. Hand-waitcnt pipelines (R10/R11/R12) all spilled
// and are permanently abandoned.
//  - __launch_bounds__(256,4): the config that compiled clean (R12's
//    (256,8) forced a 64-reg cap -> 1.3GB scratch traffic).
//  - math: two bit-identical R9 iterations per barrier -> absmax 0.0.
//  - prep: 36x256 parallel version (correctness-proven in R10-R12).

using half8  = __attribute__((ext_vector_type(8))) _Float16;
using f32x16 = __attribute__((ext_vector_type(16))) float;

__global__ void prep_kernel(const float* __restrict__ emb,
                            float* __restrict__ e2,
                            _Float16* __restrict__ eTh,
                            _Float16* __restrict__ eTl) {
    const int b = blockIdx.x;
    const int t = threadIdx.x;
    if (b < 32) {
        // h/l split: c from block (uniform), k lane-contiguous -> coalesced.
        const int c = b >> 2;                 // 0..7
        const int k = (b & 3) * 256 + t;      // 0..1023
        half8 hv, lv;
#pragma unroll
        for (int j = 0; j < 8; ++j) {
            float v = emb[(c * 8 + j) * 1024 + k];
            _Float16 h = (_Float16)v;          // same split as round 1
            hv[j] = h;
            lv[j] = (_Float16)(v - (float)h);  // exact residual
        }
        *(half8*)(eTh + k * 64 + c * 8) = hv;
        *(half8*)(eTl + k * 64 + c * 8) = lv;
    } else {
        // e2: one thread per k, ascending-d fmaf chain - bit-identical
        // op sequence to the original prep.
        const int k = (b - 32) * 256 + t;
        float s = 0.f;
#pragma unroll
        for (int d = 0; d < 64; ++d) {
            float v = emb[(d << 10) + k];
            s = fmaf(v, v, s);
        }
        e2[k] = s;
    }
}

__launch_bounds__(256, 4)
__global__ void vq_kernel(const float* __restrict__ x,
                          const _Float16* __restrict__ eTh,
                          const _Float16* __restrict__ eTl,
                          const float* __restrict__ e2,
                          const float* __restrict__ emb,
                          float* __restrict__ outq,
                          float* __restrict__ outidx) {
    // per buffer: TWO k-tiles, each (h:2048 | l:2048) halfs -> 16KB
    __shared__ __align__(16) _Float16 sB[2][8192];
    __shared__ int samin[128];

    const int tx = threadIdx.x;
    const int n0 = blockIdx.x * 128;
    const int bb = n0 >> 12;
    const int hw = n0 & 4095;
    const float* xbase = x + bb * 262144 + hw;

    const int lane = tx & 63;
    const int w    = tx >> 6;
    const int c    = lane & 31;    // 32x32 col / A-row
    const int hi   = lane >> 5;    // k-half selector
    const int pxb  = w << 5;       // wave's 32-pixel base

    // ---- A-fragments straight from global (identical values to staged) ----
    half8 ah[4], al[4];
#pragma unroll
    for (int ch = 0; ch < 4; ++ch) {
#pragma unroll
        for (int j = 0; j < 8; ++j) {
            float v = xbase[(ch * 16 + hi * 8 + j) * 4096 + pxb + c];
            _Float16 h = (_Float16)v;
            ah[ch][j] = h;
            al[ch][j] = (_Float16)(v - (float)h);
        }
    }
    asm volatile("" ::: "memory");   // keep fragments register-resident

    // ---- swizzled LDS read offsets for B (invariant over t) ----------------
    int Dofs[4];
#pragma unroll
    for (int ch = 0; ch < 4; ++ch) {
        const int y = c * 128 + ch * 32 + hi * 16;
        Dofs[ch] = y ^ ((c & 7) << 4);
    }

    // ---- staging source: pre-swizzled per-thread global byte offset --------
    const int Lb = tx * 16;                        // linear byte in 4KB tile
    const int Sb = Lb ^ (((Lb >> 7) & 7) << 4);    // sigma (self-inverse)
    const char* gH = (const char*)eTh + Sb;
    const char* gL = (const char*)eTl + Sb;

    // stages k-tiles 2*T2 and 2*T2+1 into sB[BUF]
#define STAGE2(BUF, T2)                                                       \
    {                                                                         \
        __builtin_amdgcn_global_load_lds(                                     \
            (const __attribute__((address_space(1))) unsigned int*)(gH + ((T2) << 13)), \
            (__attribute__((address_space(3))) unsigned int*)(sB[BUF] + (w << 9)),       \
            16, 0, 0);                                                        \
        __builtin_amdgcn_global_load_lds(                                     \
            (const __attribute__((address_space(1))) unsigned int*)(gL + ((T2) << 13)), \
            (__attribute__((address_space(3))) unsigned int*)(sB[BUF] + 2048 + (w << 9)),\
            16, 0, 0);                                                        \
        __builtin_amdgcn_global_load_lds(                                     \
            (const __attribute__((address_space(1))) unsigned int*)(gH + ((T2) << 13) + 4096), \
            (__attribute__((address_space(3))) unsigned int*)(sB[BUF] + 4096 + (w << 9)),       \
            16, 0, 0);                                                        \
        __builtin_amdgcn_global_load_lds(                                     \
            (const __attribute__((address_space(1))) unsigned int*)(gL + ((T2) << 13) + 4096), \
            (__attribute__((address_space(3))) unsigned int*)(sB[BUF] + 6144 + (w << 9)),       \
            16, 0, 0);                                                        \
    }

    // one verbatim R9 compute iteration on the k-tile at byte base BBASE
#define CHALF(BBASE, TT)                                                      \
    {                                                                         \
        const char* bbase_ = (BBASE);                                         \
        const float e2v_ = e2[((TT) << 5) + c];                               \
        half8 bh_[4], bl_[4];                                                 \
        _Pragma("unroll")                                                     \
        for (int ch = 0; ch < 4; ++ch) {                                      \
            bh_[ch] = *(const half8*)(bbase_ + Dofs[ch]);                     \
            bl_[ch] = *(const half8*)(bbase_ + 4096 + Dofs[ch]);              \
        }                                                                     \
        f32x16 a = {};                                                        \
        _Pragma("unroll")                                                     \
        for (int ch = 0; ch < 4; ++ch)                                        \
            a = __builtin_amdgcn_mfma_f32_32x32x16_f16(al[ch], bl_[ch], a, 0, 0, 0); \
        _Pragma("unroll")                                                     \
        for (int ch = 0; ch < 4; ++ch)                                        \
            a = __builtin_amdgcn_mfma_f32_32x32x16_f16(al[ch], bh_[ch], a, 0, 0, 0); \
        _Pragma("unroll")                                                     \
        for (int ch = 0; ch < 4; ++ch)                                        \
            a = __builtin_amdgcn_mfma_f32_32x32x16_f16(ah[ch], bl_[ch], a, 0, 0, 0); \
        _Pragma("unroll")                                                     \
        for (int ch = 0; ch < 4; ++ch)                                        \
            a = __builtin_amdgcn_mfma_f32_32x32x16_f16(ah[ch], bh_[ch], a, 0, 0, 0); \
        _Pragma("unroll")                                                     \
        for (int r = 0; r < 16; ++r) {                                        \
            float dist_ = fmaf(-2.f, a[r], e2v_);                             \
            if (dist_ < best[r]) { best[r] = dist_; bestt[r] = (TT); }        \
        }                                                                     \
    }

    float best[16];
    int   bestt[16];
#pragma unroll
    for (int i = 0; i < 16; ++i) { best[i] = 3.4e38f; bestt[i] = 0; }

    STAGE2(0, 0);
    __syncthreads();   // drains vmcnt(0): buf0 ready

#pragma unroll 1
    for (int t2 = 0; t2 < 16; ++t2) {
        const int cur = t2 & 1;
        if (t2 < 15) STAGE2(cur ^ 1, t2 + 1);     // prefetch next 16KB
        CHALF((const char*)sB[cur],        2 * t2)
        CHALF((const char*)sB[cur] + 8192, 2 * t2 + 1)
        __syncthreads();   // reads done; prefetch drained
    }

    // ---- per-pixel argmin: butterfly over the 32 cols (lanes) --------------
    // k = t*32 + c; ascending-t strict < kept earliest k per lane; cross-lane
    // merge breaks ties toward smaller k. C layout (verified m74/m101):
    // col = lane&31, row = (r&3) + 8*(r>>2) + 4*hi.
#pragma unroll
    for (int r = 0; r < 16; ++r) {
        float bv = best[r];
        int   bk = (bestt[r] << 5) + c;
#pragma unroll
        for (int m = 1; m < 32; m <<= 1) {
            float ov = __shfl_xor(bv, m, 64);
            int   ok = __shfl_xor(bk, m, 64);
            if (ov < bv || (ov == bv && ok < bk)) { bv = ov; bk = ok; }
        }
        if (c == 0) {
            const int row = (r & 3) + 8 * (r >> 2) + 4 * hi;
            samin[pxb + row] = bk;
        }
    }
    __syncthreads();

    if (tx < 128) outidx[n0 + tx] = (float)samin[tx];

    // ---- gather exact fp32 codebook rows -> output, coalesced over p -------
    const int p = tx & 127;
    const int drow = tx >> 7;                 // 0 or 1
    const int amin = samin[p];
    float* obase = outq + bb * 262144 + hw + p;
#pragma unroll
    for (int it = 0; it < 32; ++it) {
        int d = (it << 1) + drow;
        obase[d * 4096] = emb[d * 1024 + amin];
    }
}

extern "C" void kernel_launch(void* const* d_in, const int* in_sizes, int n_in,
                              void* d_out, int out_size, void* d_ws, size_t ws_size,
                              hipStream_t stream) {
    const float* x   = (const float*)d_in[0];
    const float* emb = (const float*)d_in[1];
    float* outq   = (float*)d_out;
    float* outidx = outq + 8388608;            // 32*64*64*64

    float*    e2  = (float*)d_ws;                               // 4 KB
    _Float16* eTh = (_Float16*)((char*)d_ws + 4096);            // 128 KB
    _Float16* eTl = (_Float16*)((char*)d_ws + 4096 + 131072);   // 128 KB

    prep_kernel<<<36, 256, 0, stream>>>(emb, e2, eTh, eTl);
    vq_kernel<<<1024, 256, 0, stream>>>(x, eTh, eTl, e2, emb, outq, outidx);
}